// Round 1
// baseline (18058.099 us; speedup 1.0000x reference)
//
#include <hip/hip_runtime.h>

#define NB 128      // batch
#define NH 1024     // hidden
#define NS 256      // conditioning sequence length
#define NF 8        // forecast length

typedef _Float16 half_t;
typedef _Float16 f16x8 __attribute__((ext_vector_type(8)));
typedef float f32x4 __attribute__((ext_vector_type(4)));

__device__ __forceinline__ float sigmoidf_(float x) { return 1.0f / (1.0f + expf(-x)); }

// ---------------- init: load initial hidden state (f32 + f16 copies) ----------------
__global__ void k_init(const float* __restrict__ hin, float* __restrict__ h0f,
                       float* __restrict__ h1f, half_t* __restrict__ h0h,
                       half_t* __restrict__ h1h) {
    int i = blockIdx.x * 256 + threadIdx.x;   // grid 512 -> 131072 = NB*NH
    float v0 = hin[i];
    float v1 = hin[NB * NH + i];
    h0f[i] = v0; h1f[i] = v1;
    h0h[i] = (half_t)v0; h1h[i] = (half_t)v1;
}

// ---------------- weight f32 -> f16 conversion (once per call) ----------------
__global__ void k_wcvt(const float* __restrict__ src, half_t* __restrict__ dst) {
    int i = blockIdx.x * 256 + threadIdx.x;   // over float4 quads; grid 3072 -> 3145728 elems
    float4 v = *(const float4*)(src + (size_t)i * 4);
    union { half_t h[4]; uint2 u; } cv;
    cv.h[0] = (half_t)v.x; cv.h[1] = (half_t)v.y; cv.h[2] = (half_t)v.z; cv.h[3] = (half_t)v.w;
    *(uint2*)(dst + (size_t)i * 4) = cv.u;
}

// ---------------- GRU cell kernel ----------------
// LAYER==0: gh = h0 @ Whh0^T (W1), gi = x*Wih0 (scalar input path); state = h0
// LAYER==1: gi = h0new @ Wih1^T (W1, pass0), gh = h1 @ Whh1^T (W2, pass1); state = h1
// WF16: weights already f16 in ws; else convert f32->f16 while staging.
// Block: 256 thr = 4 waves; block tile 32 batches x 32 cols x 3 gates.
// Wave (wrow,wcol in 2x2): one 16x16 MFMA tile per gate.
template<int LAYER, int WF16>
__global__ __launch_bounds__(256)
void k_cell(const half_t* __restrict__ A1,
            const half_t* __restrict__ A2,
            const void*   __restrict__ W1v,
            const void*   __restrict__ W2v,
            const float*  __restrict__ bi,
            const float*  __restrict__ bh,
            const float*  __restrict__ wih0,
            const float*  __restrict__ xp, int xstride,
            float*        __restrict__ hf32,
            half_t*       __restrict__ hout)
{
    __shared__ __align__(16) char lds[4096 + 12288];  // A tile 32x64 f16 (swz) | W tile 96x64 f16 (swz)
    const int tid  = threadIdx.x;
    const int l    = tid & 63;
    const int wv   = tid >> 6;
    const int wrow = wv >> 1, wcol = wv & 1;
    const int br   = blockIdx.x >> 5;   // 0..3  batch group
    const int bc   = blockIdx.x & 31;   // 0..31 col group

    f32x4 acc[2][3];
    #pragma unroll
    for (int p = 0; p < 2; ++p)
        #pragma unroll
        for (int g = 0; g < 3; ++g)
            #pragma unroll
            for (int q = 0; q < 4; ++q) acc[p][g][q] = 0.0f;

    const int npass = (LAYER == 1) ? 2 : 1;
    #pragma unroll
    for (int pass = 0; pass < npass; ++pass) {
        const half_t* A = (pass == 0) ? A1 : A2;
        for (int ks = 0; ks < 16; ++ks) {
            const int k0 = ks * 64;
            __syncthreads();
            // ---- stage A tile: 32 rows x 64 k (f16), XOR-swizzled
            {
                int r = tid >> 3, ko = (tid & 7) * 8;
                uint4 v = *(const uint4*)(A + (size_t)(br * 32 + r) * NH + k0 + ko);
                int off = ((r * 128 + ko * 2) ^ ((r & 7) << 4));
                *(uint4*)(lds + off) = v;
            }
            // ---- stage W tile: 96 rows (3 gates x 32 cols) x 64 k
            if (WF16) {
                const half_t* W = (const half_t*)((pass == 0) ? W1v : W2v);
                #pragma unroll
                for (int rep = 0; rep < 3; ++rep) {
                    int f = rep * 256 + tid;        // 0..767
                    int row = f >> 3;               // 0..95
                    int e8  = f & 7;                // 0..7  (8-elem chunk)
                    int g = row >> 5, c = row & 31;
                    uint4 v = *(const uint4*)(W + (size_t)(g * NH + bc * 32 + c) * NH + k0 + e8 * 8);
                    int off = 4096 + ((row * 128 + e8 * 16) ^ ((row & 7) << 4));
                    *(uint4*)(lds + off) = v;
                }
            } else {
                const float* W = (const float*)((pass == 0) ? W1v : W2v);
                #pragma unroll
                for (int rep = 0; rep < 6; ++rep) {
                    int f = rep * 256 + tid;        // 0..1535
                    int row = f >> 4;               // 0..95
                    int f4  = f & 15;               // 0..15 (4-elem chunk)
                    int g = row >> 5, c = row & 31;
                    float4 v = *(const float4*)(W + (size_t)(g * NH + bc * 32 + c) * NH + k0 + f4 * 4);
                    union { half_t h[4]; uint2 u; } cv;
                    cv.h[0] = (half_t)v.x; cv.h[1] = (half_t)v.y;
                    cv.h[2] = (half_t)v.z; cv.h[3] = (half_t)v.w;
                    int off = 4096 + ((row * 128 + f4 * 8) ^ ((row & 7) << 4));
                    *(uint2*)(lds + off) = cv.u;
                }
            }
            __syncthreads();
            // ---- MFMA: 2 k-chunks of 32
            #pragma unroll
            for (int kc = 0; kc < 2; ++kc) {
                int kb = kc * 64 + (l >> 4) * 16;           // byte offset within 128B row
                int ar = wrow * 16 + (l & 15);
                f16x8 af = *(const f16x8*)(lds + ((ar * 128 + kb) ^ ((ar & 7) << 4)));
                #pragma unroll
                for (int g = 0; g < 3; ++g) {
                    int wr = g * 32 + wcol * 16 + (l & 15);
                    f16x8 bf = *(const f16x8*)(lds + 4096 + ((wr * 128 + kb) ^ ((wr & 7) << 4)));
                    acc[pass][g] = __builtin_amdgcn_mfma_f32_16x16x32_f16(af, bf, acc[pass][g], 0, 0, 0);
                }
            }
        }
    }

    // ---- epilogue: gates + state update
    int c = bc * 32 + wcol * 16 + (l & 15);
    float bic[3], bhc[3], wx[3];
    #pragma unroll
    for (int g = 0; g < 3; ++g) { bic[g] = bi[g * NH + c]; bhc[g] = bh[g * NH + c]; wx[g] = 0.f; }
    if (LAYER == 0) {
        #pragma unroll
        for (int g = 0; g < 3; ++g) wx[g] = wih0[g * NH + c];
    }
    #pragma unroll
    for (int q = 0; q < 4; ++q) {
        int b = br * 32 + wrow * 16 + (l >> 4) * 4 + q;
        float gi[3], gh[3];
        if (LAYER == 0) {
            float xv = xp[(size_t)b * xstride];
            #pragma unroll
            for (int g = 0; g < 3; ++g) {
                gi[g] = xv * wx[g] + bic[g];
                gh[g] = acc[0][g][q] + bhc[g];
            }
        } else {
            #pragma unroll
            for (int g = 0; g < 3; ++g) {
                gi[g] = acc[0][g][q] + bic[g];
                gh[g] = acc[1][g][q] + bhc[g];
            }
        }
        float r_ = sigmoidf_(gi[0] + gh[0]);
        float z_ = sigmoidf_(gi[1] + gh[1]);
        float n_ = tanhf(gi[2] + r_ * gh[2]);
        size_t idx = (size_t)b * NH + c;
        float hp = hf32[idx];
        float hn = (1.0f - z_) * n_ + z_ * hp;
        hf32[idx] = hn;
        hout[idx] = (half_t)hn;
    }
}

// ---------------- fc head: y[b] = h1[b,:] . fc_w + fc_b ----------------
__global__ void k_fc(const float* __restrict__ h1, const float* __restrict__ fcw,
                     const float* __restrict__ fcb, float* __restrict__ yo) {
    int b = blockIdx.x, l = threadIdx.x;   // 128 blocks x 64 threads
    float s = 0.f;
    #pragma unroll
    for (int j = 0; j < 16; ++j) s += h1[(size_t)b * NH + j * 64 + l] * fcw[j * 64 + l];
    #pragma unroll
    for (int m = 32; m > 0; m >>= 1) s += __shfl_xor(s, m);
    if (l == 0) yo[b] = s + fcb[0];
}

// ---------------- final: mean of 8 forecasts + copy h_final ----------------
__global__ void k_final(const float* __restrict__ ys, const float* __restrict__ h0f,
                        const float* __restrict__ h1f, float* __restrict__ out) {
    int i = blockIdx.x * 256 + threadIdx.x;
    if (i < NB) {
        float s = 0.f;
        #pragma unroll
        for (int k = 0; k < NF; ++k) s += ys[k * NB + i];
        out[i] = s * 0.125f;
    }
    int j = i - NB;
    if (j >= 0 && j < 2 * NB * NH) {
        out[NB + j] = (j < NB * NH) ? h0f[j] : h1f[j - NB * NH];
    }
}

extern "C" void kernel_launch(void* const* d_in, const int* in_sizes, int n_in,
                              void* d_out, int out_size, void* d_ws, size_t ws_size,
                              hipStream_t stream)
{
    const float* x    = (const float*)d_in[0];
    const float* h0in = (const float*)d_in[1];
    const float* Wih0 = (const float*)d_in[2];
    const float* Whh0 = (const float*)d_in[3];
    const float* bih0 = (const float*)d_in[4];
    const float* bhh0 = (const float*)d_in[5];
    const float* Wih1 = (const float*)d_in[6];
    const float* Whh1 = (const float*)d_in[7];
    const float* bih1 = (const float*)d_in[8];
    const float* bhh1 = (const float*)d_in[9];
    const float* fcw  = (const float*)d_in[10];
    const float* fcb  = (const float*)d_in[11];

    char* ws = (char*)d_ws;
    const size_t WBYTES = (size_t)3072 * 1024 * sizeof(half_t);   // 6 MiB per matrix
    const size_t need   = 3 * WBYTES + 4 * 524288 + 4096;
    const bool wf16 = (ws_size >= need);

    size_t off = 0;
    half_t *w0 = nullptr, *w1 = nullptr, *w2 = nullptr;
    if (wf16) {
        w0 = (half_t*)(ws);
        w1 = (half_t*)(ws + WBYTES);
        w2 = (half_t*)(ws + 2 * WBYTES);
        off = 3 * WBYTES;
    }
    float* h0f = (float*)(ws + off); off += 524288;
    float* h1f = (float*)(ws + off); off += 524288;
    half_t* h0h[2] = { (half_t*)(ws + off), (half_t*)(ws + off + 262144) }; off += 524288;
    half_t* h1h[2] = { (half_t*)(ws + off), (half_t*)(ws + off + 262144) }; off += 524288;
    float* ys = (float*)(ws + off);

    if (wf16) {
        k_wcvt<<<3072, 256, 0, stream>>>(Whh0, w0);
        k_wcvt<<<3072, 256, 0, stream>>>(Wih1, w1);
        k_wcvt<<<3072, 256, 0, stream>>>(Whh1, w2);
    }
    k_init<<<512, 256, 0, stream>>>(h0in, h0f, h1f, h0h[0], h1h[0]);

    int p0 = 0, p1 = 0;
    dim3 gC(128), bC(256);

    // ---- conditioning: 256 steps
    for (int t = 0; t < NS; ++t) {
        if (wf16) k_cell<0, 1><<<gC, bC, 0, stream>>>(h0h[p0], nullptr, w0,   nullptr, bih0, bhh0, Wih0, x + t, NS, h0f, h0h[p0 ^ 1]);
        else      k_cell<0, 0><<<gC, bC, 0, stream>>>(h0h[p0], nullptr, Whh0, nullptr, bih0, bhh0, Wih0, x + t, NS, h0f, h0h[p0 ^ 1]);
        p0 ^= 1;
        if (wf16) k_cell<1, 1><<<gC, bC, 0, stream>>>(h0h[p0], h1h[p1], w1,   w2,   bih1, bhh1, nullptr, nullptr, 0, h1f, h1h[p1 ^ 1]);
        else      k_cell<1, 0><<<gC, bC, 0, stream>>>(h0h[p0], h1h[p1], Wih1, Whh1, bih1, bhh1, nullptr, nullptr, 0, h1f, h1h[p1 ^ 1]);
        p1 ^= 1;
    }
    k_fc<<<128, 64, 0, stream>>>(h1f, fcw, fcb, ys);   // y0

    // ---- forecast: 7 autoregressive steps
    for (int i = 1; i < NF; ++i) {
        if (wf16) k_cell<0, 1><<<gC, bC, 0, stream>>>(h0h[p0], nullptr, w0,   nullptr, bih0, bhh0, Wih0, ys + (i - 1) * NB, 1, h0f, h0h[p0 ^ 1]);
        else      k_cell<0, 0><<<gC, bC, 0, stream>>>(h0h[p0], nullptr, Whh0, nullptr, bih0, bhh0, Wih0, ys + (i - 1) * NB, 1, h0f, h0h[p0 ^ 1]);
        p0 ^= 1;
        if (wf16) k_cell<1, 1><<<gC, bC, 0, stream>>>(h0h[p0], h1h[p1], w1,   w2,   bih1, bhh1, nullptr, nullptr, 0, h1f, h1h[p1 ^ 1]);
        else      k_cell<1, 0><<<gC, bC, 0, stream>>>(h0h[p0], h1h[p1], Wih1, Whh1, bih1, bhh1, nullptr, nullptr, 0, h1f, h1h[p1 ^ 1]);
        p1 ^= 1;
        k_fc<<<128, 64, 0, stream>>>(h1f, fcw, fcb, ys + i * NB);
    }

    k_final<<<1025, 256, 0, stream>>>(ys, h0f, h1f, (float*)d_out);
}

// Round 2
// 11781.841 us; speedup vs baseline: 1.5327x; 1.5327x over previous
//
#include <hip/hip_runtime.h>

#define NB 128      // batch
#define NH 1024     // hidden
#define NS 256      // conditioning sequence length
#define NF 8        // forecast length
#define NBLK 192    // persistent blocks: 64 L0 | 64 GI | 64 GH
#define NTH 256     // 4 waves

typedef _Float16 half_t;
typedef _Float16 f16x8 __attribute__((ext_vector_type(8)));
typedef float f32x4 __attribute__((ext_vector_type(4)));

struct GP {
    const float *x, *Wih0, *Whh0, *bih0, *bhh0, *Wih1, *Whh1, *bih1, *bhh1, *fcw, *fcb;
    float *h0f, *h1f, *gib0, *gib1, *ys, *out;
    half_t *h0b0, *h0b1, *h1b0, *h1b1;
    unsigned *bar;
};

__device__ __forceinline__ float fast_sigmoid(float x) { return 1.0f / (1.0f + __expf(-x)); }
__device__ __forceinline__ float fast_tanh(float x) {
    float e = __expf(2.0f * x);
    return (e - 1.0f) / (e + 1.0f);
}

// sense-reversing grid barrier: cnt at bar[0], gen at bar[32] (separate 128B lines)
__device__ __forceinline__ void gsync(unsigned* bar) {
    __syncthreads();
    if (threadIdx.x == 0) {
        __threadfence();
        unsigned g = __hip_atomic_load(bar + 32, __ATOMIC_RELAXED, __HIP_MEMORY_SCOPE_AGENT);
        unsigned v = __hip_atomic_fetch_add(bar, 1u, __ATOMIC_ACQ_REL, __HIP_MEMORY_SCOPE_AGENT);
        if (v == NBLK - 1) {
            __hip_atomic_store(bar, 0u, __ATOMIC_RELAXED, __HIP_MEMORY_SCOPE_AGENT);
            __hip_atomic_fetch_add(bar + 32, 1u, __ATOMIC_RELEASE, __HIP_MEMORY_SCOPE_AGENT);
        } else {
            while (__hip_atomic_load(bar + 32, __ATOMIC_ACQUIRE, __HIP_MEMORY_SCOPE_AGENT) == g)
                __builtin_amdgcn_s_sleep(1);
        }
        __threadfence();
    }
    __syncthreads();
}

// ---------------- init: initial hidden state (f32 master + f16 copies) ----------------
__global__ void k_init(const float* __restrict__ hin, float* __restrict__ h0f,
                       float* __restrict__ h1f, half_t* __restrict__ h0h,
                       half_t* __restrict__ h1h) {
    int i = blockIdx.x * 256 + threadIdx.x;   // grid 512 -> 131072 = NB*NH
    float v0 = hin[i];
    float v1 = hin[NB * NH + i];
    h0f[i] = v0; h1f[i] = v1;
    h0h[i] = (half_t)v0; h1h[i] = (half_t)v1;
}

// ---------------- persistent GRU kernel ----------------
__global__ __launch_bounds__(NTH)
void k_gru(GP p) {
    extern __shared__ char lds[];             // 48 rows x 1024 f16 = 96 KiB, XOR-swizzled
    const int tid = threadIdx.x;
    const int l   = tid & 63;
    const int wv  = tid >> 6;
    const int bid = blockIdx.x;
    const int role = (bid < 64) ? 0 : (bid < 128 ? 1 : 2);
    const int bc   = bid & 63;
    const int colbase = bc * 16;

    // ---- one-time: load W slice (3 gates x 16 cols x 1024 k) f32 -> f16 into LDS
    {
        const float* Wsrc = (role == 0) ? p.Whh0 : ((role == 1) ? p.Wih1 : p.Whh1);
        for (int i = tid; i < 12288; i += NTH) {   // float4 chunks: 48 rows x 256
            int row = i >> 8, j = i & 255;
            int g = row >> 4, r = row & 15;
            float4 v = *(const float4*)(Wsrc + (size_t)(g * NH + colbase + r) * NH + j * 4);
            union { half_t h[4]; uint2 u; } cv;
            cv.h[0] = (half_t)v.x; cv.h[1] = (half_t)v.y;
            cv.h[2] = (half_t)v.z; cv.h[3] = (half_t)v.w;
            *(uint2*)(lds + (row * 2048 + ((j * 8) ^ ((row & 7) << 4)))) = cv.u;
        }
        __syncthreads();
    }

    // ---- per-role constants
    const int c = colbase + (l & 15);
    float bi_[3] = {0,0,0}, bh_[3] = {0,0,0}, wx_[3] = {0,0,0};
    if (role == 0) {
        #pragma unroll
        for (int g = 0; g < 3; ++g) {
            bi_[g] = p.bih0[g * NH + c]; bh_[g] = p.bhh0[g * NH + c];
            wx_[g] = p.Wih0[g * NH + c];
        }
    } else if (role == 2) {
        #pragma unroll
        for (int g = 0; g < 3; ++g) {
            bi_[g] = p.bih1[g * NH + c]; bh_[g] = p.bhh1[g * NH + c];
        }
    }

    // precomputed swizzle constants for B-fragment reads (rows r0,r1,r2 per gate)
    const int rr[3] = { (l & 15), 16 + (l & 15), 32 + (l & 15) };
    const int rbase[3] = { rr[0] * 2048, rr[1] * 2048, rr[2] * 2048 };
    const int rmask[3] = { (rr[0] & 7) << 4, (rr[1] & 7) << 4, (rr[2] & 7) << 4 };
    const int kb0 = (l >> 4) << 4;            // byte offset of this lane's k-chunk
    const int arow = wv * 32 + (l & 15);      // A row for M-tile 0 of this wave
    const int b0base = wv * 32 + ((l >> 4) << 2);  // first output row (q=0)

    auto do_gemm = [&](const half_t* __restrict__ A, f32x4 (&acc)[2][3]) {
        const half_t* a0p = A + (size_t)arow * NH + ((l >> 4) << 3);
        #pragma unroll 4
        for (int ks = 0; ks < 32; ++ks) {
            f16x8 a0 = *(const f16x8*)(a0p + ks * 32);
            f16x8 a1 = *(const f16x8*)(a0p + 16 * NH + ks * 32);
            int kb = ks * 64 + kb0;
            #pragma unroll
            for (int g = 0; g < 3; ++g) {
                f16x8 bf = *(const f16x8*)(lds + rbase[g] + (kb ^ rmask[g]));
                acc[0][g] = __builtin_amdgcn_mfma_f32_16x16x32_f16(a0, bf, acc[0][g], 0, 0, 0);
                acc[1][g] = __builtin_amdgcn_mfma_f32_16x16x32_f16(a1, bf, acc[1][g], 0, 0, 0);
            }
        }
    };

    auto l0_epi = [&](const float* xptr, int xstride, f32x4 (&acc)[2][3], half_t* hw) {
        #pragma unroll
        for (int m = 0; m < 2; ++m) {
            #pragma unroll
            for (int q = 0; q < 4; ++q) {
                int b = b0base + m * 16 + q;
                float xv = xptr[b * xstride];
                float gh0 = acc[m][0][q] + bh_[0];
                float gh1 = acc[m][1][q] + bh_[1];
                float gh2 = acc[m][2][q] + bh_[2];
                float r_ = fast_sigmoid(xv * wx_[0] + bi_[0] + gh0);
                float z_ = fast_sigmoid(xv * wx_[1] + bi_[1] + gh1);
                float n_ = fast_tanh(xv * wx_[2] + bi_[2] + r_ * gh2);
                int idx = b * NH + c;
                float hp = p.h0f[idx];
                float hn = (1.0f - z_) * n_ + z_ * hp;
                p.h0f[idx] = hn;
                hw[idx] = (half_t)hn;
            }
        }
    };

    auto gi_epi = [&](f32x4 (&acc)[2][3], float* gw) {
        #pragma unroll
        for (int m = 0; m < 2; ++m)
            #pragma unroll
            for (int g = 0; g < 3; ++g)
                *(f32x4*)(gw + (g * NH + c) * NB + b0base + m * 16) = acc[m][g];
    };

    auto gh_epi = [&](f32x4 (&acc)[2][3], const float* gr, half_t* hw) {
        #pragma unroll
        for (int m = 0; m < 2; ++m) {
            f32x4 gv[3];
            #pragma unroll
            for (int g = 0; g < 3; ++g)
                gv[g] = *(const f32x4*)(gr + (g * NH + c) * NB + b0base + m * 16);
            #pragma unroll
            for (int q = 0; q < 4; ++q) {
                int b = b0base + m * 16 + q;
                float gh0 = acc[m][0][q] + bh_[0];
                float gh1 = acc[m][1][q] + bh_[1];
                float gh2 = acc[m][2][q] + bh_[2];
                float r_ = fast_sigmoid(gv[0][q] + bi_[0] + gh0);
                float z_ = fast_sigmoid(gv[1][q] + bi_[1] + gh1);
                float n_ = fast_tanh(gv[2][q] + bi_[2] + r_ * gh2);
                int idx = b * NH + c;
                float hp = p.h1f[idx];
                float hn = (1.0f - z_) * n_ + z_ * hp;
                p.h1f[idx] = hn;
                hw[idx] = (half_t)hn;
            }
        }
    };

    auto do_fc = [&](float* dst) {
        if (bid == 0) {
            int row = tid >> 1, hf = tid & 1;
            const float* hp = p.h1f + row * NH + hf * 512;
            const float* wp = p.fcw + hf * 512;
            float s = 0.0f;
            #pragma unroll 4
            for (int j = 0; j < 512; j += 4) {
                float4 a = *(const float4*)(hp + j);
                float4 w = *(const float4*)(wp + j);
                s += a.x * w.x + a.y * w.y + a.z * w.z + a.w * w.w;
            }
            s += __shfl_xor(s, 1);
            if (hf == 0) dst[row] = s + p.fcb[0];
        }
    };

    int cur0 = 0, cur1 = 0, gcur = 0;   // parity trackers (uniform across all blocks)
    f32x4 zero4 = {0.f, 0.f, 0.f, 0.f};

    // ---- conditioning: phases 0 .. NS+1 (3-stage pipeline)
    for (int ph = 0; ph < NS + 2; ++ph) {
        if (role == 0 && ph < NS) {
            f32x4 acc[2][3];
            #pragma unroll
            for (int m = 0; m < 2; ++m) { acc[m][0] = zero4; acc[m][1] = zero4; acc[m][2] = zero4; }
            do_gemm(cur0 ? p.h0b1 : p.h0b0, acc);
            l0_epi(p.x + ph, NS, acc, cur0 ? p.h0b0 : p.h0b1);
        } else if (role == 1 && ph >= 1 && ph <= NS) {
            f32x4 acc[2][3];
            #pragma unroll
            for (int m = 0; m < 2; ++m) { acc[m][0] = zero4; acc[m][1] = zero4; acc[m][2] = zero4; }
            do_gemm(cur0 ? p.h0b1 : p.h0b0, acc);
            gi_epi(acc, gcur ? p.gib0 : p.gib1);
        } else if (role == 2 && ph >= 2) {
            f32x4 acc[2][3];
            #pragma unroll
            for (int m = 0; m < 2; ++m) { acc[m][0] = zero4; acc[m][1] = zero4; acc[m][2] = zero4; }
            do_gemm(cur1 ? p.h1b1 : p.h1b0, acc);
            gh_epi(acc, gcur ? p.gib1 : p.gib0, cur1 ? p.h1b0 : p.h1b1);
        }
        gsync(p.bar);
        if (ph < NS) cur0 ^= 1;
        if (ph >= 1 && ph <= NS) gcur ^= 1;
        if (ph >= 2) cur1 ^= 1;
    }

    // ---- forecast: 7 autoregressive steps (fc -> L0 -> GI -> GH)
    for (int i = 1; i < NF; ++i) {
        do_fc(p.ys + (i - 1) * NB);
        gsync(p.bar);
        if (role == 0) {
            f32x4 acc[2][3];
            #pragma unroll
            for (int m = 0; m < 2; ++m) { acc[m][0] = zero4; acc[m][1] = zero4; acc[m][2] = zero4; }
            do_gemm(cur0 ? p.h0b1 : p.h0b0, acc);
            l0_epi(p.ys + (i - 1) * NB, 1, acc, cur0 ? p.h0b0 : p.h0b1);
        }
        gsync(p.bar); cur0 ^= 1;
        if (role == 1) {
            f32x4 acc[2][3];
            #pragma unroll
            for (int m = 0; m < 2; ++m) { acc[m][0] = zero4; acc[m][1] = zero4; acc[m][2] = zero4; }
            do_gemm(cur0 ? p.h0b1 : p.h0b0, acc);
            gi_epi(acc, gcur ? p.gib0 : p.gib1);
        }
        gsync(p.bar); gcur ^= 1;
        if (role == 2) {
            f32x4 acc[2][3];
            #pragma unroll
            for (int m = 0; m < 2; ++m) { acc[m][0] = zero4; acc[m][1] = zero4; acc[m][2] = zero4; }
            do_gemm(cur1 ? p.h1b1 : p.h1b0, acc);
            gh_epi(acc, gcur ? p.gib1 : p.gib0, cur1 ? p.h1b0 : p.h1b1);
        }
        gsync(p.bar); cur1 ^= 1;
    }
    do_fc(p.ys + 7 * NB);
    gsync(p.bar);

    // ---- final output: mean of 8 forecasts + h_final copy
    if (bid == 0 && tid < NB) {
        float s = 0.0f;
        #pragma unroll
        for (int k = 0; k < NF; ++k) s += p.ys[k * NB + tid];
        p.out[tid] = s * 0.125f;
    }
    for (int j = bid * NTH + tid; j < 2 * NB * NH; j += NBLK * NTH)
        p.out[NB + j] = (j < NB * NH) ? p.h0f[j] : p.h1f[j - NB * NH];
}

extern "C" void kernel_launch(void* const* d_in, const int* in_sizes, int n_in,
                              void* d_out, int out_size, void* d_ws, size_t ws_size,
                              hipStream_t stream)
{
    GP p;
    p.x    = (const float*)d_in[0];
    const float* h0in = (const float*)d_in[1];
    p.Wih0 = (const float*)d_in[2];
    p.Whh0 = (const float*)d_in[3];
    p.bih0 = (const float*)d_in[4];
    p.bhh0 = (const float*)d_in[5];
    p.Wih1 = (const float*)d_in[6];
    p.Whh1 = (const float*)d_in[7];
    p.bih1 = (const float*)d_in[8];
    p.bhh1 = (const float*)d_in[9];
    p.fcw  = (const float*)d_in[10];
    p.fcb  = (const float*)d_in[11];
    p.out  = (float*)d_out;

    char* ws = (char*)d_ws;
    p.bar  = (unsigned*)ws;                      ws += 256;
    p.h0f  = (float*)ws;                         ws += 524288;
    p.h1f  = (float*)ws;                         ws += 524288;
    p.h0b0 = (half_t*)ws;                        ws += 262144;
    p.h0b1 = (half_t*)ws;                        ws += 262144;
    p.h1b0 = (half_t*)ws;                        ws += 262144;
    p.h1b1 = (half_t*)ws;                        ws += 262144;
    p.gib0 = (float*)ws;                         ws += 1572864;
    p.gib1 = (float*)ws;                         ws += 1572864;
    p.ys   = (float*)ws;                         ws += 4096;

    hipMemsetAsync(p.bar, 0, 256, stream);
    k_init<<<512, 256, 0, stream>>>(h0in, p.h0f, p.h1f, p.h0b0, p.h1b0);

    void* args[] = { &p };
    if (hipLaunchCooperativeKernel((void*)k_gru, dim3(NBLK), dim3(NTH), args,
                                   96 * 1024, stream) != hipSuccess) {
        (void)hipGetLastError();
        // fallback: plain launch — grid=192 blocks @96KiB LDS = 1/CU, co-resident on 256 CUs
        k_gru<<<dim3(NBLK), dim3(NTH), 96 * 1024, stream>>>(p);
    }
}

// Round 3
// 6392.185 us; speedup vs baseline: 2.8250x; 1.8432x over previous
//
#include <hip/hip_runtime.h>

#define NB 128      // batch
#define NH 1024     // hidden
#define NS 256      // conditioning sequence length
#define NF 8        // forecast length
#define NBLK 192    // persistent blocks: 64 L0 | 64 GI | 64 GH
#define NTH 512     // 8 waves
#define AG  __HIP_MEMORY_SCOPE_AGENT

typedef _Float16 half_t;
typedef _Float16 f16x8 __attribute__((ext_vector_type(8)));
typedef float f32x4 __attribute__((ext_vector_type(4)));
typedef unsigned long long u64;

struct GP {
    const float *x, *hin, *Wih0, *Whh0, *bih0, *bhh0, *Wih1, *Whh1, *bih1, *bhh1, *fcw, *fcb;
    float *gib0, *gib1, *ys, *out;
    half_t *h0b0, *h0b1, *h1b0, *h1b1;
    unsigned *bar;
};

__device__ __forceinline__ float fast_sigmoid(float x) { return 1.0f / (1.0f + __expf(-x)); }
__device__ __forceinline__ float fast_tanh(float x) {
    float e = __expf(2.0f * x);
    return (e - 1.0f) / (e + 1.0f);
}

// relaxed agent-scope coherent accesses (per-line; NO cache-wide maintenance)
__device__ __forceinline__ u64 ldu64(const void* p) {
    return __hip_atomic_load((const u64*)p, __ATOMIC_RELAXED, AG);
}
__device__ __forceinline__ void stu64(void* p, u64 v) {
    __hip_atomic_store((u64*)p, v, __ATOMIC_RELAXED, AG);
}
__device__ __forceinline__ float ldf32(const float* p) {
    return __hip_atomic_load(p, __ATOMIC_RELAXED, AG);
}
__device__ __forceinline__ void stf32(float* p, float v) {
    __hip_atomic_store(p, v, __ATOMIC_RELAXED, AG);
}

// monotone-counter grid barrier: no reset, no generation, relaxed atomics only.
// __syncthreads() drains each wave's vmem (compiler emits waitcnt vmcnt(0) before
// s_barrier), so all block stores are MALL-visible before thread0 arrives.
__device__ __forceinline__ void gsync(unsigned* bar, unsigned target) {
    __syncthreads();
    if (threadIdx.x == 0) {
        asm volatile("s_waitcnt vmcnt(0)" ::: "memory");
        __hip_atomic_fetch_add(bar, 1u, __ATOMIC_RELAXED, AG);
        while (__hip_atomic_load(bar, __ATOMIC_RELAXED, AG) < target)
            __builtin_amdgcn_s_sleep(2);
    }
    __syncthreads();
}

// ---------------- init: f16 copies of initial hidden state ----------------
__global__ void k_init(const float* __restrict__ hin, half_t* __restrict__ h0h,
                       half_t* __restrict__ h1h) {
    int i = blockIdx.x * 256 + threadIdx.x;   // 512 blocks -> 131072 = NB*NH
    h0h[i] = (half_t)hin[i];
    h1h[i] = (half_t)hin[NB * NH + i];
}

// ---------------- persistent GRU kernel ----------------
__global__ __launch_bounds__(NTH)
void k_gru(GP p) {
    extern __shared__ char lds[];   // [0,96K): W 48x1024 f16 swz | [96K,104K): h master 128x16 f32
    const int tid = threadIdx.x;
    const int l   = tid & 63;
    const int wv  = tid >> 6;               // 0..7
    const int bid = blockIdx.x;
    const int role = (bid < 64) ? 0 : (bid < 128 ? 1 : 2);
    const int bc   = bid & 63;
    const int colbase = bc * 16;
    float* hl = (float*)(lds + 98304);      // block-private h master (roles 0,2)

    // ---- one-time: W slice (3 gates x 16 cols x 1024 k) f32 -> f16 into LDS
    {
        const float* Wsrc = (role == 0) ? p.Whh0 : ((role == 1) ? p.Wih1 : p.Whh1);
        for (int i = tid; i < 12288; i += NTH) {   // float4 chunks: 48 rows x 256
            int row = i >> 8, j = i & 255;
            int g = row >> 4, r = row & 15;
            float4 v = *(const float4*)(Wsrc + (size_t)(g * NH + colbase + r) * NH + j * 4);
            union { half_t h[4]; uint2 u; } cv;
            cv.h[0] = (half_t)v.x; cv.h[1] = (half_t)v.y;
            cv.h[2] = (half_t)v.z; cv.h[3] = (half_t)v.w;
            *(uint2*)(lds + (row * 2048 + ((j * 8) ^ ((row & 7) << 4)))) = cv.u;
        }
        // ---- one-time: h master f32 into LDS (roles 0 and 2)
        if (role != 1) {
            const float* hsrc = p.hin + (role == 2 ? NB * NH : 0);
            for (int i = tid; i < NB * 16; i += NTH) {
                int b = i >> 4, cl = i & 15;
                hl[i] = hsrc[(size_t)b * NH + colbase + cl];
            }
        }
        __syncthreads();
    }

    // ---- per-role constants (read-only, plain cached loads -> registers)
    const int cloc = l & 15;
    const int c = colbase + cloc;
    float bi_[3] = {0,0,0}, bh_[3] = {0,0,0}, wx_[3] = {0,0,0};
    if (role == 0) {
        #pragma unroll
        for (int g = 0; g < 3; ++g) {
            bi_[g] = p.bih0[g * NH + c]; bh_[g] = p.bhh0[g * NH + c];
            wx_[g] = p.Wih0[g * NH + c];
        }
    } else if (role == 2) {
        #pragma unroll
        for (int g = 0; g < 3; ++g) {
            bi_[g] = p.bih1[g * NH + c]; bh_[g] = p.bhh1[g * NH + c];
        }
    }

    const int rbase[3] = { cloc * 2048, (16 + cloc) * 2048, (32 + cloc) * 2048 };
    const int rmask[3] = { (cloc & 7) << 4, (cloc & 7) << 4, (cloc & 7) << 4 };
    const int kb0 = (l >> 4) << 4;                 // byte offset of lane's k-chunk
    const int arow = wv * 16 + cloc;               // A row this lane loads
    const int b0base = wv * 16 + ((l >> 4) << 2);  // first output batch row

    auto do_gemm = [&](const half_t* __restrict__ A, f32x4 (&acc)[3]) {
        const u64* ap = (const u64*)(A + (size_t)arow * NH) + ((l >> 4) << 1);
        #pragma unroll 8
        for (int ks = 0; ks < 32; ++ks) {
            union { u64 u[2]; f16x8 v; } a;
            a.u[0] = ldu64(ap + ks * 8);
            a.u[1] = ldu64(ap + ks * 8 + 1);
            int kb = ks * 64 + kb0;
            #pragma unroll
            for (int g = 0; g < 3; ++g) {
                f16x8 bf = *(const f16x8*)(lds + rbase[g] + (kb ^ rmask[g]));
                acc[g] = __builtin_amdgcn_mfma_f32_16x16x32_f16(a.v, bf, acc[g], 0, 0, 0);
            }
        }
    };

    // pack 4 lanes' f16 h-values (consecutive c) into one u64, store coherent
    auto pack_store_h = [&](half_t* hw, int b, float hn) {
        unsigned v = (unsigned)__builtin_bit_cast(unsigned short, (half_t)hn);
        unsigned o = __shfl_xor(v, 1);
        unsigned pair = (l & 1) ? (o | (v << 16)) : (v | (o << 16));
        unsigned p2 = __shfl_xor(pair, 2);
        u64 quad = (l & 2) ? (((u64)pair << 32) | p2) : ((u64)pair | ((u64)p2 << 32));
        if ((l & 3) == 0) stu64(hw + (size_t)b * NH + (c & ~3), quad);
    };

    auto l0_epi = [&](const float* xptr, int xstride, f32x4 (&acc)[3], half_t* hw) {
        #pragma unroll
        for (int q = 0; q < 4; ++q) {
            int b = b0base + q;
            float xv = ldf32(xptr + (size_t)b * xstride);
            float gh0 = acc[0][q] + bh_[0];
            float gh1 = acc[1][q] + bh_[1];
            float gh2 = acc[2][q] + bh_[2];
            float r_ = fast_sigmoid(xv * wx_[0] + bi_[0] + gh0);
            float z_ = fast_sigmoid(xv * wx_[1] + bi_[1] + gh1);
            float n_ = fast_tanh(xv * wx_[2] + bi_[2] + r_ * gh2);
            float hp = hl[b * 16 + cloc];
            float hn = (1.0f - z_) * n_ + z_ * hp;
            hl[b * 16 + cloc] = hn;
            pack_store_h(hw, b, hn);
        }
    };

    auto gi_epi = [&](f32x4 (&acc)[3], float* gw) {
        #pragma unroll
        for (int g = 0; g < 3; ++g) {
            union { f32x4 v; u64 u[2]; } t; t.v = acc[g];
            float* dst = gw + ((size_t)g * NH + c) * NB + b0base;
            stu64(dst, t.u[0]);
            stu64(dst + 2, t.u[1]);
        }
    };

    auto gh_epi = [&](f32x4 (&acc)[3], const float* gr, half_t* hw) {
        f32x4 gv[3];
        #pragma unroll
        for (int g = 0; g < 3; ++g) {
            union { f32x4 v; u64 u[2]; } t;
            const float* src = gr + ((size_t)g * NH + c) * NB + b0base;
            t.u[0] = ldu64(src);
            t.u[1] = ldu64(src + 2);
            gv[g] = t.v;
        }
        #pragma unroll
        for (int q = 0; q < 4; ++q) {
            int b = b0base + q;
            float gh0 = acc[0][q] + bh_[0];
            float gh1 = acc[1][q] + bh_[1];
            float gh2 = acc[2][q] + bh_[2];
            float r_ = fast_sigmoid(gv[0][q] + bi_[0] + gh0);
            float z_ = fast_sigmoid(gv[1][q] + bi_[1] + gh1);
            float n_ = fast_tanh(gv[2][q] + bi_[2] + r_ * gh2);
            float hp = hl[b * 16 + cloc];
            float hn = (1.0f - z_) * n_ + z_ * hp;
            hl[b * 16 + cloc] = hn;
            pack_store_h(hw, b, hn);
        }
    };

    // fc head: y[b] = h1[b,:].w + fcb  (reads f16 h1 buffer, block 0 only)
    auto do_fc = [&](const half_t* h1c, float* dst) {
        if (bid == 0) {
            int row = tid >> 2, qt = tid & 3;
            const u64* hp = (const u64*)(h1c + (size_t)row * NH) + qt * 64;
            const float4* wp = (const float4*)(p.fcw) + qt * 64;
            float s = 0.0f;
            #pragma unroll 4
            for (int j = 0; j < 64; ++j) {
                union { u64 u; half_t h[4]; } cv; cv.u = ldu64(hp + j);
                float4 w = wp[j];
                s += (float)cv.h[0] * w.x + (float)cv.h[1] * w.y
                   + (float)cv.h[2] * w.z + (float)cv.h[3] * w.w;
            }
            s += __shfl_xor(s, 1);
            s += __shfl_xor(s, 2);
            if (qt == 0) stf32(dst + row, s + p.fcb[0]);
        }
    };

    unsigned tgt = 0;
    auto SYNC = [&]() { tgt += NBLK; gsync(p.bar, tgt); };

    int cur0 = 0, cur1 = 0, gcur = 0;
    f32x4 zero4 = {0.f, 0.f, 0.f, 0.f};

    // ---- conditioning: phases 0 .. NS+1 (3-stage pipeline)
    for (int ph = 0; ph < NS + 2; ++ph) {
        if (role == 0 && ph < NS) {
            f32x4 acc[3] = {zero4, zero4, zero4};
            do_gemm(cur0 ? p.h0b1 : p.h0b0, acc);
            l0_epi(p.x + ph, NS, acc, cur0 ? p.h0b0 : p.h0b1);
        } else if (role == 1 && ph >= 1 && ph <= NS) {
            f32x4 acc[3] = {zero4, zero4, zero4};
            do_gemm(cur0 ? p.h0b1 : p.h0b0, acc);
            gi_epi(acc, gcur ? p.gib0 : p.gib1);
        } else if (role == 2 && ph >= 2) {
            f32x4 acc[3] = {zero4, zero4, zero4};
            do_gemm(cur1 ? p.h1b1 : p.h1b0, acc);
            gh_epi(acc, gcur ? p.gib1 : p.gib0, cur1 ? p.h1b0 : p.h1b1);
        }
        SYNC();
        if (ph < NS) cur0 ^= 1;
        if (ph >= 1 && ph <= NS) gcur ^= 1;
        if (ph >= 2) cur1 ^= 1;
    }

    // ---- forecast: 7 autoregressive steps (fc -> L0 -> GI -> GH)
    for (int i = 1; i < NF; ++i) {
        do_fc(cur1 ? p.h1b1 : p.h1b0, p.ys + (i - 1) * NB);
        SYNC();
        if (role == 0) {
            f32x4 acc[3] = {zero4, zero4, zero4};
            do_gemm(cur0 ? p.h0b1 : p.h0b0, acc);
            l0_epi(p.ys + (i - 1) * NB, 1, acc, cur0 ? p.h0b0 : p.h0b1);
        }
        SYNC(); cur0 ^= 1;
        if (role == 1) {
            f32x4 acc[3] = {zero4, zero4, zero4};
            do_gemm(cur0 ? p.h0b1 : p.h0b0, acc);
            gi_epi(acc, gcur ? p.gib0 : p.gib1);
        }
        SYNC(); gcur ^= 1;
        if (role == 2) {
            f32x4 acc[3] = {zero4, zero4, zero4};
            do_gemm(cur1 ? p.h1b1 : p.h1b0, acc);
            gh_epi(acc, gcur ? p.gib1 : p.gib0, cur1 ? p.h1b0 : p.h1b1);
        }
        SYNC(); cur1 ^= 1;
    }
    do_fc(cur1 ? p.h1b1 : p.h1b0, p.ys + 7 * NB);
    SYNC();

    // ---- final output: mean of forecasts + h_final export from LDS
    if (bid == 0 && tid < NB) {
        float s = 0.0f;
        #pragma unroll
        for (int k = 0; k < NF; ++k) s += ldf32(p.ys + k * NB + tid);
        p.out[tid] = s * 0.125f;
    }
    if (role != 1) {
        float* ob = p.out + NB + (role == 2 ? (size_t)NB * NH : 0);
        for (int i = tid; i < NB * 16; i += NTH) {
            int b = i >> 4, cl = i & 15;
            ob[(size_t)b * NH + colbase + cl] = hl[i];
        }
    }
}

extern "C" void kernel_launch(void* const* d_in, const int* in_sizes, int n_in,
                              void* d_out, int out_size, void* d_ws, size_t ws_size,
                              hipStream_t stream)
{
    GP p;
    p.x    = (const float*)d_in[0];
    p.hin  = (const float*)d_in[1];
    p.Wih0 = (const float*)d_in[2];
    p.Whh0 = (const float*)d_in[3];
    p.bih0 = (const float*)d_in[4];
    p.bhh0 = (const float*)d_in[5];
    p.Wih1 = (const float*)d_in[6];
    p.Whh1 = (const float*)d_in[7];
    p.bih1 = (const float*)d_in[8];
    p.bhh1 = (const float*)d_in[9];
    p.fcw  = (const float*)d_in[10];
    p.fcb  = (const float*)d_in[11];
    p.out  = (float*)d_out;

    char* ws = (char*)d_ws;
    p.bar  = (unsigned*)ws;                      ws += 256;
    p.h0b0 = (half_t*)ws;                        ws += 262144;
    p.h0b1 = (half_t*)ws;                        ws += 262144;
    p.h1b0 = (half_t*)ws;                        ws += 262144;
    p.h1b1 = (half_t*)ws;                        ws += 262144;
    p.gib0 = (float*)ws;                         ws += 1572864;
    p.gib1 = (float*)ws;                         ws += 1572864;
    p.ys   = (float*)ws;                         ws += 4096;

    hipMemsetAsync(p.bar, 0, 256, stream);
    k_init<<<512, 256, 0, stream>>>(p.hin, p.h0b0, p.h1b0);

    void* args[] = { &p };
    if (hipLaunchCooperativeKernel((void*)k_gru, dim3(NBLK), dim3(NTH), args,
                                   106496, stream) != hipSuccess) {
        (void)hipGetLastError();
        // fallback: 192 blocks @104KiB LDS = 1 block/CU on 256 CUs -> co-resident
        k_gru<<<dim3(NBLK), dim3(NTH), 106496, stream>>>(p);
    }
}

// Round 4
// 4003.938 us; speedup vs baseline: 4.5101x; 1.5965x over previous
//
#include <hip/hip_runtime.h>

#define NB 128      // batch
#define NH 1024     // hidden
#define NS 256      // conditioning sequence length
#define NF 8        // forecast length
#define NBLK 192    // persistent blocks: 64 L0 | 64 GI | 64 GH
#define NTH 512     // 8 waves
#define AG  __HIP_MEMORY_SCOPE_AGENT

// barrier line indices (uint32 units; lines 128B apart)
#define GLOBL 0
#define XARR  32          // +32*xcd
#define XRELL (32*9)      // +32*xcd
#define XCPY  (32*17)     // +32*xcd
#define XCNT  (32*25)     // +32*xcd
#define INITL (32*33)

typedef _Float16 half_t;
typedef _Float16 f16x8 __attribute__((ext_vector_type(8)));
typedef float f32x4 __attribute__((ext_vector_type(4)));
typedef unsigned long long u64;

struct GP {
    const float *x, *hin, *Wih0, *Whh0, *bih0, *bhh0, *Wih1, *Whh1, *bih1, *bhh1, *fcw, *fcb;
    float *gib0, *gib1, *ys, *out;
    half_t *h0b0, *h0b1, *h1b0, *h1b1;
    char *reg;            // XCD-private A regions: [8 xcd][2 slot][h0 256K | h1 256K]
    unsigned *bar;
};

__device__ __forceinline__ float fast_sigmoid(float x) { return 1.0f / (1.0f + __expf(-x)); }
__device__ __forceinline__ float fast_tanh(float x) {
    float e = __expf(2.0f * x);
    return (e - 1.0f) / (e + 1.0f);
}

// relaxed agent-scope (sc1 / MALL-coherent) accesses
__device__ __forceinline__ u64 ldu64(const void* p) {
    return __hip_atomic_load((const u64*)p, __ATOMIC_RELAXED, AG);
}
__device__ __forceinline__ void stu64(void* p, u64 v) {
    __hip_atomic_store((u64*)p, v, __ATOMIC_RELAXED, AG);
}
__device__ __forceinline__ float ldf32(const float* p) {
    return __hip_atomic_load(p, __ATOMIC_RELAXED, AG);
}
__device__ __forceinline__ void stf32(float* p, float v) {
    __hip_atomic_store(p, v, __ATOMIC_RELAXED, AG);
}
__device__ __forceinline__ unsigned aadd(unsigned* p, unsigned v) {
    return __hip_atomic_fetch_add(p, v, __ATOMIC_RELAXED, AG);
}
__device__ __forceinline__ unsigned ald(const unsigned* p) {
    return __hip_atomic_load(p, __ATOMIC_RELAXED, AG);
}

// ---------------- init: f16 copies of initial hidden state ----------------
__global__ void k_init(const float* __restrict__ hin, half_t* __restrict__ h0h,
                       half_t* __restrict__ h1h) {
    int i = blockIdx.x * 256 + threadIdx.x;   // 512 blocks -> 131072 = NB*NH
    h0h[i] = (half_t)hin[i];
    h1h[i] = (half_t)hin[NB * NH + i];
}

// ---------------- persistent GRU kernel ----------------
__global__ __launch_bounds__(NTH)
void k_gru(GP p) {
    extern __shared__ char lds[];   // [0,96K) W swz | [96K..) h master 8K | meta @104K
    const int tid = threadIdx.x;
    const int l   = tid & 63;
    const int wv  = tid >> 6;               // 0..7
    const int bid = blockIdx.x;
    const int role = (bid < 64) ? 0 : (bid < 128 ? 1 : 2);
    const int bc   = bid & 63;
    const int colbase = bc * 16;
    float* hl  = (float*)(lds + 98304);     // block-private h master (roles 0,2)
    int* meta  = (int*)(lds + 106496);
    unsigned* bar = p.bar;

    // ---- one-time: W slice (3 gates x 16 cols x 1024 k) f32 -> f16 into LDS
    {
        const float* Wsrc = (role == 0) ? p.Whh0 : ((role == 1) ? p.Wih1 : p.Whh1);
        for (int i = tid; i < 12288; i += NTH) {   // float4 chunks: 48 rows x 256
            int row = i >> 8, j = i & 255;
            int g = row >> 4, r = row & 15;
            float4 v = *(const float4*)(Wsrc + (size_t)(g * NH + colbase + r) * NH + j * 4);
            union { half_t h[4]; uint2 u; } cv;
            cv.h[0] = (half_t)v.x; cv.h[1] = (half_t)v.y;
            cv.h[2] = (half_t)v.z; cv.h[3] = (half_t)v.w;
            *(uint2*)(lds + (row * 2048 + ((j * 8) ^ ((row & 7) << 4)))) = cv.u;
        }
        if (role != 1) {   // h master f32 into LDS
            const float* hsrc = p.hin + (role == 2 ? NB * NH : 0);
            for (int i = tid; i < NB * 16; i += NTH) {
                int b = i >> 4, cl = i & 15;
                hl[i] = hsrc[(size_t)b * NH + colbase + cl];
            }
        }
    }

    // ---- one-time: XCD discovery + registration + flat init barrier
    if (tid == 0) {
        unsigned x;
        asm volatile("s_getreg_b32 %0, hwreg(HW_REG_XCC_ID)" : "=s"(x));
        x &= 7;
        unsigned r = aadd(bar + XCNT + x * 32, 1u);
        asm volatile("s_waitcnt vmcnt(0)" ::: "memory");
        aadd(bar + INITL, 1u);
        while (ald(bar + INITL) < NBLK) __builtin_amdgcn_s_sleep(1);
        int nn = 0, cnt = 0;
        for (int k = 0; k < 8; ++k) {
            unsigned c = ald(bar + XCNT + k * 32);
            if (c) ++cnt;
            if (k == (int)x) nn = (int)c;
        }
        meta[0] = (int)x; meta[1] = (int)r; meta[2] = nn; meta[3] = cnt;
    }
    __syncthreads();
    const int xcd_  = meta[0];
    const int rank_ = meta[1];
    const int n_    = meta[2];
    const int nx_   = meta[3];

    // ---- per-role constants
    const int cloc = l & 15;
    const int c = colbase + cloc;
    float bi_[3] = {0,0,0}, bh_[3] = {0,0,0}, wx_[3] = {0,0,0};
    if (role == 0) {
        #pragma unroll
        for (int g = 0; g < 3; ++g) {
            bi_[g] = p.bih0[g * NH + c]; bh_[g] = p.bhh0[g * NH + c];
            wx_[g] = p.Wih0[g * NH + c];
        }
    } else if (role == 2) {
        #pragma unroll
        for (int g = 0; g < 3; ++g) {
            bi_[g] = p.bih1[g * NH + c]; bh_[g] = p.bhh1[g * NH + c];
        }
    }

    const int rbase[3] = { cloc * 2048, (16 + cloc) * 2048, (32 + cloc) * 2048 };
    const int rmask = (cloc & 7) << 4;
    const int kb0 = (l >> 4) << 4;                 // byte offset of lane's k-chunk
    const int arow = wv * 16 + cloc;               // A row this lane needs
    const int b0base = wv * 16 + ((l >> 4) << 2);  // first output batch row
    const int aloff = (l >> 4) * 2048 + arow * 16; // lane offset in region [kq][row] layout

    // ---- hierarchical global barrier (+ per-CU L1 invalidate on exit)
    auto gbar = [&](unsigned t) {
        __syncthreads();
        if (tid == 0) {
            asm volatile("s_waitcnt vmcnt(0)" ::: "memory");
            aadd(bar + XARR + xcd_ * 32, 1u);
            if (rank_ == 0) {
                while (ald(bar + XARR + xcd_ * 32) < (unsigned)n_ * t) __builtin_amdgcn_s_sleep(1);
                aadd(bar + GLOBL, 1u);
                while (ald(bar + GLOBL) < (unsigned)nx_ * t) __builtin_amdgcn_s_sleep(1);
                __hip_atomic_store(bar + XRELL + xcd_ * 32, t, __ATOMIC_RELAXED, AG);
            } else {
                while (ald(bar + XRELL + xcd_ * 32) < t) __builtin_amdgcn_s_sleep(1);
            }
        }
        __syncthreads();
        asm volatile("buffer_inv" ::: "memory");   // L1-only invalidate (no L2 writeback)
    };

    // ---- per-phase: pull fresh h into this XCD's region (transposed [kq][row])
    auto xcopy = [&](const half_t* h0s, const half_t* h1s, int slot) {
        char* dst = p.reg + ((size_t)(xcd_ * 2 + slot)) * 524288;
        for (int idx = rank_ * 512 + tid; idx < 32768; idx += n_ * 512) {
            int which = idx >> 14, kq = (idx >> 7) & 127, row = idx & 127;
            const half_t* s = (which ? h1s : h0s) + row * 1024 + kq * 8;
            union { u64 u[2]; uint4 v; } t;
            t.u[0] = ldu64(s);
            t.u[1] = ldu64(s + 4);
            *(uint4*)(dst + which * 262144 + (size_t)(kq * 128 + row) * 16) = t.v;
        }
    };
    auto csync = [&](unsigned ct) {   // XCD-local barrier after copy
        __syncthreads();
        if (tid == 0) {
            asm volatile("s_waitcnt vmcnt(0)" ::: "memory");
            aadd(bar + XCPY + xcd_ * 32, 1u);
            while (ald(bar + XCPY + xcd_ * 32) < (unsigned)n_ * ct) __builtin_amdgcn_s_sleep(1);
        }
        __syncthreads();
    };

    // ---- GEMM: A from XCD region (plain cached loads), W from LDS
    auto do_gemm = [&](const char* regA, f32x4 (&acc)[3]) {
        const char* ap = regA + aloff;
        #pragma unroll 8
        for (int ks = 0; ks < 32; ++ks) {
            f16x8 a = *(const f16x8*)(ap + (size_t)ks * 8192);
            int kb = ks * 64 + kb0;
            #pragma unroll
            for (int g = 0; g < 3; ++g) {
                f16x8 bf = *(const f16x8*)(lds + rbase[g] + (kb ^ rmask));
                acc[g] = __builtin_amdgcn_mfma_f32_16x16x32_f16(a, bf, acc[g], 0, 0, 0);
            }
        }
    };

    // pack 4 lanes' f16 h-values into one u64, store coherent (sc1)
    auto pack_store_h = [&](half_t* hw, int b, float hn) {
        unsigned v = (unsigned)__builtin_bit_cast(unsigned short, (half_t)hn);
        unsigned o = __shfl_xor(v, 1);
        unsigned pair = (l & 1) ? (o | (v << 16)) : (v | (o << 16));
        unsigned p2 = __shfl_xor(pair, 2);
        u64 quad = (l & 2) ? (((u64)pair << 32) | p2) : ((u64)pair | ((u64)p2 << 32));
        if ((l & 3) == 0) stu64(hw + (size_t)b * NH + (c & ~3), quad);
    };

    auto l0_epi = [&](const float xv[4], f32x4 (&acc)[3], half_t* hw) {
        #pragma unroll
        for (int q = 0; q < 4; ++q) {
            int b = b0base + q;
            float gh0 = acc[0][q] + bh_[0];
            float gh1 = acc[1][q] + bh_[1];
            float gh2 = acc[2][q] + bh_[2];
            float r_ = fast_sigmoid(xv[q] * wx_[0] + bi_[0] + gh0);
            float z_ = fast_sigmoid(xv[q] * wx_[1] + bi_[1] + gh1);
            float n_2 = fast_tanh(xv[q] * wx_[2] + bi_[2] + r_ * gh2);
            float hp = hl[b * 16 + cloc];
            float hn = (1.0f - z_) * n_2 + z_ * hp;
            hl[b * 16 + cloc] = hn;
            pack_store_h(hw, b, hn);
        }
    };

    auto gi_epi = [&](f32x4 (&acc)[3], float* gw) {
        #pragma unroll
        for (int g = 0; g < 3; ++g) {
            union { f32x4 v; u64 u[2]; } t; t.v = acc[g];
            float* dst = gw + ((size_t)g * NH + c) * NB + b0base;
            stu64(dst, t.u[0]);
            stu64(dst + 2, t.u[1]);
        }
    };

    auto gh_epi = [&](f32x4 (&acc)[3], const f32x4 gv[3], half_t* hw) {
        #pragma unroll
        for (int q = 0; q < 4; ++q) {
            int b = b0base + q;
            float gh0 = acc[0][q] + bh_[0];
            float gh1 = acc[1][q] + bh_[1];
            float gh2 = acc[2][q] + bh_[2];
            float r_ = fast_sigmoid(gv[0][q] + bi_[0] + gh0);
            float z_ = fast_sigmoid(gv[1][q] + bi_[1] + gh1);
            float n_2 = fast_tanh(gv[2][q] + bi_[2] + r_ * gh2);
            float hp = hl[b * 16 + cloc];
            float hn = (1.0f - z_) * n_2 + z_ * hp;
            hl[b * 16 + cloc] = hn;
            pack_store_h(hw, b, hn);
        }
    };

    auto load_gi = [&](const float* gr, f32x4 (&gv)[3]) {
        #pragma unroll
        for (int g = 0; g < 3; ++g) {
            union { f32x4 v; u64 u[2]; } t;
            const float* src = gr + ((size_t)g * NH + c) * NB + b0base;
            t.u[0] = ldu64(src);
            t.u[1] = ldu64(src + 2);
            gv[g] = t.v;
        }
    };

    // fc head from region h1 copy (plain cached loads), block 0 only
    auto do_fc = [&](const char* regH1, float* dst) {
        if (bid == 0) {
            int row = tid >> 2, part = tid & 3;
            const char* hp = regH1 + (size_t)row * 16;
            const float4* wp = (const float4*)p.fcw;
            float s = 0.0f;
            #pragma unroll 8
            for (int kk = 0; kk < 32; ++kk) {
                int kq = part * 32 + kk;
                union { f16x8 v; half_t h[8]; } a;
                a.v = *(const f16x8*)(hp + (size_t)kq * 2048);
                float4 w0 = wp[kq * 2], w1 = wp[kq * 2 + 1];
                s += (float)a.h[0]*w0.x + (float)a.h[1]*w0.y + (float)a.h[2]*w0.z + (float)a.h[3]*w0.w
                   + (float)a.h[4]*w1.x + (float)a.h[5]*w1.y + (float)a.h[6]*w1.z + (float)a.h[7]*w1.w;
            }
            s += __shfl_xor(s, 1);
            s += __shfl_xor(s, 2);
            if (part == 0) stf32(dst + row, s + p.fcb[0]);
        }
    };

    unsigned tgt = 0, ctgt = 0;
    int cur0 = 0, cur1 = 0, gcur = 0;
    f32x4 zero4 = {0.f, 0.f, 0.f, 0.f};

    auto COPY = [&]() {   // stage current read-buffers into region, return slot base
        ++ctgt;
        int slot = (int)(ctgt & 1);
        xcopy(cur0 ? p.h0b1 : p.h0b0, cur1 ? p.h1b1 : p.h1b0, slot);
        csync(ctgt);
        return p.reg + ((size_t)(xcd_ * 2 + slot)) * 524288;
    };

    // ---- conditioning: phases 0 .. NS+1 (3-stage pipeline)
    for (int ph = 0; ph < NS + 2; ++ph) {
        const char* regB = COPY();
        if (role == 0 && ph < NS) {
            float xv[4];
            #pragma unroll
            for (int q = 0; q < 4; ++q) xv[q] = ldf32(p.x + (size_t)(b0base + q) * NS + ph);
            f32x4 acc[3] = {zero4, zero4, zero4};
            do_gemm(regB, acc);
            l0_epi(xv, acc, cur0 ? p.h0b0 : p.h0b1);
        } else if (role == 1 && ph >= 1 && ph <= NS) {
            f32x4 acc[3] = {zero4, zero4, zero4};
            do_gemm(regB, acc);
            gi_epi(acc, gcur ? p.gib0 : p.gib1);
        } else if (role == 2 && ph >= 2) {
            f32x4 gv[3];
            load_gi(gcur ? p.gib1 : p.gib0, gv);
            f32x4 acc[3] = {zero4, zero4, zero4};
            do_gemm(regB + 262144, acc);
            gh_epi(acc, gv, cur1 ? p.h1b0 : p.h1b1);
        }
        ++tgt; gbar(tgt);
        if (ph < NS) cur0 ^= 1;
        if (ph >= 1 && ph <= NS) gcur ^= 1;
        if (ph >= 2) cur1 ^= 1;
    }

    // ---- forecast: 7 autoregressive steps (fc -> L0 -> GI -> GH)
    for (int i = 1; i < NF; ++i) {
        const char* regB = COPY();
        do_fc(regB + 262144, p.ys + (i - 1) * NB);
        ++tgt; gbar(tgt);

        regB = COPY();
        if (role == 0) {
            float xv[4];
            #pragma unroll
            for (int q = 0; q < 4; ++q) xv[q] = ldf32(p.ys + (i - 1) * NB + b0base + q);
            f32x4 acc[3] = {zero4, zero4, zero4};
            do_gemm(regB, acc);
            l0_epi(xv, acc, cur0 ? p.h0b0 : p.h0b1);
        }
        ++tgt; gbar(tgt); cur0 ^= 1;

        regB = COPY();
        if (role == 1) {
            f32x4 acc[3] = {zero4, zero4, zero4};
            do_gemm(regB, acc);
            gi_epi(acc, gcur ? p.gib0 : p.gib1);
        }
        ++tgt; gbar(tgt); gcur ^= 1;

        regB = COPY();
        if (role == 2) {
            f32x4 gv[3];
            load_gi(gcur ? p.gib1 : p.gib0, gv);
            f32x4 acc[3] = {zero4, zero4, zero4};
            do_gemm(regB + 262144, acc);
            gh_epi(acc, gv, cur1 ? p.h1b0 : p.h1b1);
        }
        ++tgt; gbar(tgt); cur1 ^= 1;
    }
    {
        const char* regB = COPY();
        do_fc(regB + 262144, p.ys + 7 * NB);
        ++tgt; gbar(tgt);
    }

    // ---- final output: mean of forecasts + h_final export from LDS
    if (bid == 0 && tid < NB) {
        float s = 0.0f;
        #pragma unroll
        for (int k = 0; k < NF; ++k) s += ldf32(p.ys + k * NB + tid);
        p.out[tid] = s * 0.125f;
    }
    if (role != 1) {
        float* ob = p.out + NB + (role == 2 ? (size_t)NB * NH : 0);
        for (int i = tid; i < NB * 16; i += NTH) {
            int b = i >> 4, cl = i & 15;
            ob[(size_t)b * NH + colbase + cl] = hl[i];
        }
    }
}

extern "C" void kernel_launch(void* const* d_in, const int* in_sizes, int n_in,
                              void* d_out, int out_size, void* d_ws, size_t ws_size,
                              hipStream_t stream)
{
    GP p;
    p.x    = (const float*)d_in[0];
    p.hin  = (const float*)d_in[1];
    p.Wih0 = (const float*)d_in[2];
    p.Whh0 = (const float*)d_in[3];
    p.bih0 = (const float*)d_in[4];
    p.bhh0 = (const float*)d_in[5];
    p.Wih1 = (const float*)d_in[6];
    p.Whh1 = (const float*)d_in[7];
    p.bih1 = (const float*)d_in[8];
    p.bhh1 = (const float*)d_in[9];
    p.fcw  = (const float*)d_in[10];
    p.fcb  = (const float*)d_in[11];
    p.out  = (float*)d_out;

    char* ws = (char*)d_ws;
    p.bar  = (unsigned*)ws;                      ws += 8192;
    p.h0b0 = (half_t*)ws;                        ws += 262144;
    p.h0b1 = (half_t*)ws;                        ws += 262144;
    p.h1b0 = (half_t*)ws;                        ws += 262144;
    p.h1b1 = (half_t*)ws;                        ws += 262144;
    p.gib0 = (float*)ws;                         ws += 1572864;
    p.gib1 = (float*)ws;                         ws += 1572864;
    p.ys   = (float*)ws;                         ws += 4096;
    ws = (char*)(((size_t)ws + 4095) & ~(size_t)4095);
    p.reg  = ws;                                 ws += 8 * 2 * 524288;   // 8 MiB

    hipMemsetAsync(p.bar, 0, 8192, stream);
    k_init<<<512, 256, 0, stream>>>(p.hin, p.h0b0, p.h1b0);

    void* args[] = { &p };
    if (hipLaunchCooperativeKernel((void*)k_gru, dim3(NBLK), dim3(NTH), args,
                                   106752, stream) != hipSuccess) {
        (void)hipGetLastError();
        // fallback: 192 blocks @ ~104KiB LDS = 1 block/CU on 256 CUs -> co-resident
        k_gru<<<dim3(NBLK), dim3(NTH), 106752, stream>>>(p);
    }
}

// Round 5
// 3315.616 us; speedup vs baseline: 5.4464x; 1.2076x over previous
//
#include <hip/hip_runtime.h>

#define NB 128      // batch
#define NH 1024     // hidden
#define NS 256      // conditioning sequence length
#define NF 8        // forecast length
#define NBLK 192    // persistent blocks: 64 L0 | 64 GI | 64 GH
#define NTH 512     // 8 waves
#define AG  __HIP_MEMORY_SCOPE_AGENT

// barrier line indices (uint32 units; distinct 128B lines)
#define GLOBL 0
#define RELL  64
#define INITL 128
#define XCNT  192          // +32*xcd
#define XARR  512          // +32*xcd   (XCD-local L2 lines)
#define XCPY  1024         // +32*xcd   (XCD-local L2 lines)

typedef _Float16 half_t;
typedef _Float16 f16x8 __attribute__((ext_vector_type(8)));
typedef float f32x4 __attribute__((ext_vector_type(4)));
typedef unsigned long long u64;

struct GP {
    const float *x, *hin, *Wih0, *Whh0, *bih0, *bhh0, *Wih1, *Whh1, *bih1, *bhh1, *fcw, *fcb;
    float *gib0, *gib1, *ys, *out;
    half_t *h0b0, *h0b1, *h1b0, *h1b1;
    char *reg;            // XCD-private A regions: [8 xcd][2 slot][h0 256K | h1 256K]
    unsigned *bar;
};

__device__ __forceinline__ float fast_sigmoid(float x) { return 1.0f / (1.0f + __expf(-x)); }
__device__ __forceinline__ float fast_tanh(float x) {
    float e = __expf(2.0f * x);
    return (e - 1.0f) / (e + 1.0f);
}

// ---- agent-scope (sc1 / MALL) accesses ----
__device__ __forceinline__ u64 ldu64(const void* p) {
    return __hip_atomic_load((const u64*)p, __ATOMIC_RELAXED, AG);
}
__device__ __forceinline__ void stu64(void* p, u64 v) {
    __hip_atomic_store((u64*)p, v, __ATOMIC_RELAXED, AG);
}
__device__ __forceinline__ float ldf32(const float* p) {
    return __hip_atomic_load(p, __ATOMIC_RELAXED, AG);
}
__device__ __forceinline__ unsigned aadd(unsigned* p, unsigned v) {
    return __hip_atomic_fetch_add(p, v, __ATOMIC_RELAXED, AG);
}
__device__ __forceinline__ unsigned ald(const unsigned* p) {
    return __hip_atomic_load(p, __ATOMIC_RELAXED, AG);
}

// ---- XCD-local (no sc1 -> executes in the local XCD's L2) atomics ----
__device__ __forceinline__ void l2add(unsigned* p, unsigned v) {
    asm volatile("global_atomic_add %0, %1, off" :: "v"(p), "v"(v) : "memory");
}
__device__ __forceinline__ unsigned l2add_rtn(unsigned* p, unsigned v) {
    unsigned ret;
    asm volatile("global_atomic_add %0, %1, %2, off sc0\n\ts_waitcnt vmcnt(0)"
                 : "=v"(ret) : "v"(p), "v"(v) : "memory");
    return ret;
}

// ---------------- init: f16 copies of h0 + ys seeded with fc bias ----------------
__global__ void k_init(const float* __restrict__ hin, half_t* __restrict__ h0h,
                       half_t* __restrict__ h1h, const float* __restrict__ fcb,
                       float* __restrict__ ys) {
    int i = blockIdx.x * 256 + threadIdx.x;   // 512 blocks -> 131072 = NB*NH
    h0h[i] = (half_t)hin[i];
    h1h[i] = (half_t)hin[NB * NH + i];
    if (blockIdx.x == 0) {
        float fb = fcb[0];
        for (int j = threadIdx.x; j < NF * NB; j += 256) ys[j] = fb;
    }
}

// ---------------- persistent GRU kernel ----------------
__global__ __launch_bounds__(NTH)
void k_gru(GP p) {
    extern __shared__ char lds[];   // [0,96K) W swz | [96K..) h master 8K | meta @104K
    const int tid = threadIdx.x;
    const int l   = tid & 63;
    const int wv  = tid >> 6;               // 0..7
    const int bid = blockIdx.x;
    const int role = (bid < 64) ? 0 : (bid < 128 ? 1 : 2);
    const int bc   = bid & 63;
    const int colbase = bc * 16;
    float* hl  = (float*)(lds + 98304);     // block-private h master (roles 0,2)
    int* meta  = (int*)(lds + 106496);
    unsigned* bar = p.bar;

    // ---- one-time: W slice (3 gates x 16 cols x 1024 k) f32 -> f16 into LDS
    {
        const float* Wsrc = (role == 0) ? p.Whh0 : ((role == 1) ? p.Wih1 : p.Whh1);
        for (int i = tid; i < 12288; i += NTH) {   // float4 chunks: 48 rows x 256
            int row = i >> 8, j = i & 255;
            int g = row >> 4, r = row & 15;
            float4 v = *(const float4*)(Wsrc + (size_t)(g * NH + colbase + r) * NH + j * 4);
            union { half_t h[4]; uint2 u; } cv;
            cv.h[0] = (half_t)v.x; cv.h[1] = (half_t)v.y;
            cv.h[2] = (half_t)v.z; cv.h[3] = (half_t)v.w;
            *(uint2*)(lds + (row * 2048 + ((j * 8) ^ ((row & 7) << 4)))) = cv.u;
        }
        if (role != 1) {   // h master f32 into LDS
            const float* hsrc = p.hin + (role == 2 ? NB * NH : 0);
            for (int i = tid; i < NB * 16; i += NTH) {
                int b = i >> 4, cl = i & 15;
                hl[i] = hsrc[(size_t)b * NH + colbase + cl];
            }
        }
    }

    // ---- one-time: XCD discovery + registration + flat init barrier (AG scope)
    if (tid == 0) {
        unsigned x;
        asm volatile("s_getreg_b32 %0, hwreg(HW_REG_XCC_ID)" : "=s"(x));
        x &= 7;
        unsigned r = aadd(bar + XCNT + x * 32, 1u);
        asm volatile("s_waitcnt vmcnt(0)" ::: "memory");
        aadd(bar + INITL, 1u);
        while (ald(bar + INITL) < NBLK) __builtin_amdgcn_s_sleep(1);
        int nn = 0, cnt = 0;
        for (int k = 0; k < 8; ++k) {
            unsigned c = ald(bar + XCNT + k * 32);
            if (c) ++cnt;
            if (k == (int)x) nn = (int)c;
        }
        meta[0] = (int)x; meta[1] = (int)r; meta[2] = nn; meta[3] = cnt;
    }
    __syncthreads();
    const int xcd_  = meta[0];
    const int rank_ = meta[1];
    const int n_    = meta[2];
    const int nx_   = meta[3];

    // ---- per-role constants
    const int cloc = l & 15;
    const int c = colbase + cloc;
    float bi_[3] = {0,0,0}, bh_[3] = {0,0,0}, wx_[3] = {0,0,0}, fcwv = 0.f;
    if (role == 0) {
        #pragma unroll
        for (int g = 0; g < 3; ++g) {
            bi_[g] = p.bih0[g * NH + c]; bh_[g] = p.bhh0[g * NH + c];
            wx_[g] = p.Wih0[g * NH + c];
        }
    } else if (role == 2) {
        #pragma unroll
        for (int g = 0; g < 3; ++g) {
            bi_[g] = p.bih1[g * NH + c]; bh_[g] = p.bhh1[g * NH + c];
        }
        fcwv = p.fcw[c];
    }

    const int rbase[3] = { cloc * 2048, (16 + cloc) * 2048, (32 + cloc) * 2048 };
    const int rmask = (cloc & 7) << 4;
    const int kb0 = (l >> 4) << 4;                 // byte offset of lane's k-chunk
    const int arow = wv * 16 + cloc;               // A row this lane needs
    const int b0base = wv * 16 + ((l >> 4) << 2);  // first output batch row
    const int aloff = (l >> 4) * 2048 + arow * 16; // lane offset in region [kq][row] layout

    // ---- global barrier: L2-local aggregate -> single MALL line -> flat release
    auto gbar = [&](unsigned t) {
        __syncthreads();
        if (tid == 0) {
            l2add(bar + XARR + xcd_ * 32, 1u);
            if (rank_ == 0) {
                while (l2add_rtn(bar + XARR + xcd_ * 32, 0u) < (unsigned)n_ * t)
                    __builtin_amdgcn_s_sleep(1);
                unsigned old = aadd(bar + GLOBL, 1u);
                if (old == (unsigned)nx_ * t - 1u) aadd(bar + RELL, 1u);
            }
            while (ald(bar + RELL) < t) __builtin_amdgcn_s_sleep(1);
        }
        __syncthreads();
        asm volatile("buffer_inv" ::: "memory");   // L1-only invalidate
    };

    // ---- per-phase: pull fresh h into this XCD's region (transposed [kq][row])
    auto xcopy = [&](const half_t* h0s, const half_t* h1s, int slot) {
        char* dst = p.reg + ((size_t)(xcd_ * 2 + slot)) * 524288;
        for (int idx = rank_ * 512 + tid; idx < 32768; idx += n_ * 512) {
            int which = idx >> 14, kq = (idx >> 7) & 127, row = idx & 127;
            const half_t* s = (which ? h1s : h0s) + row * 1024 + kq * 8;
            union { u64 u[2]; uint4 v; } t;
            t.u[0] = ldu64(s);
            t.u[1] = ldu64(s + 4);
            *(uint4*)(dst + which * 262144 + (size_t)(kq * 128 + row) * 16) = t.v;
        }
    };
    auto csync = [&](unsigned ct) {   // XCD-local copy barrier (local L2 atomics)
        __syncthreads();
        if (tid == 0) {
            l2add(bar + XCPY + xcd_ * 32, 1u);
            while (l2add_rtn(bar + XCPY + xcd_ * 32, 0u) < (unsigned)n_ * ct)
                __builtin_amdgcn_s_sleep(1);
        }
        __syncthreads();
    };

    // ---- GEMM: A from XCD region (plain cached loads), W from LDS
    auto do_gemm = [&](const char* regA, f32x4 (&acc)[3]) {
        const char* ap = regA + aloff;
        #pragma unroll 8
        for (int ks = 0; ks < 32; ++ks) {
            f16x8 a = *(const f16x8*)(ap + (size_t)ks * 8192);
            int kb = ks * 64 + kb0;
            #pragma unroll
            for (int g = 0; g < 3; ++g) {
                f16x8 bf = *(const f16x8*)(lds + rbase[g] + (kb ^ rmask));
                acc[g] = __builtin_amdgcn_mfma_f32_16x16x32_f16(a, bf, acc[g], 0, 0, 0);
            }
        }
    };

    // pack 4 lanes' f16 h-values into one u64, store coherent (sc1)
    auto pack_store_h = [&](half_t* hw, int b, float hn) {
        unsigned v = (unsigned)__builtin_bit_cast(unsigned short, (half_t)hn);
        unsigned o = __shfl_xor(v, 1);
        unsigned pair = (l & 1) ? (o | (v << 16)) : (v | (o << 16));
        unsigned p2 = __shfl_xor(pair, 2);
        u64 quad = (l & 2) ? (((u64)pair << 32) | p2) : ((u64)pair | ((u64)p2 << 32));
        if ((l & 3) == 0) stu64(hw + (size_t)b * NH + (c & ~3), quad);
    };

    auto l0_epi = [&](const float xv[4], f32x4 (&acc)[3], half_t* hw) {
        #pragma unroll
        for (int q = 0; q < 4; ++q) {
            int b = b0base + q;
            float gh0 = acc[0][q] + bh_[0];
            float gh1 = acc[1][q] + bh_[1];
            float gh2 = acc[2][q] + bh_[2];
            float r_ = fast_sigmoid(xv[q] * wx_[0] + bi_[0] + gh0);
            float z_ = fast_sigmoid(xv[q] * wx_[1] + bi_[1] + gh1);
            float n_2 = fast_tanh(xv[q] * wx_[2] + bi_[2] + r_ * gh2);
            float hp = hl[b * 16 + cloc];
            float hn = (1.0f - z_) * n_2 + z_ * hp;
            hl[b * 16 + cloc] = hn;
            pack_store_h(hw, b, hn);
        }
    };

    auto gi_epi = [&](f32x4 (&acc)[3], float* gw) {
        #pragma unroll
        for (int g = 0; g < 3; ++g) {
            union { f32x4 v; u64 u[2]; } t; t.v = acc[g];
            float* dst = gw + ((size_t)g * NH + c) * NB + b0base;
            stu64(dst, t.u[0]);
            stu64(dst + 2, t.u[1]);
        }
    };

    // role-2 epilogue; optionally accumulates fc partial dot into ydst (device atomics)
    auto gh_epi = [&](f32x4 (&acc)[3], const f32x4 gv[3], half_t* hw, float* ydst) {
        float hn4[4];
        #pragma unroll
        for (int q = 0; q < 4; ++q) {
            int b = b0base + q;
            float gh0 = acc[0][q] + bh_[0];
            float gh1 = acc[1][q] + bh_[1];
            float gh2 = acc[2][q] + bh_[2];
            float r_ = fast_sigmoid(gv[0][q] + bi_[0] + gh0);
            float z_ = fast_sigmoid(gv[1][q] + bi_[1] + gh1);
            float n_2 = fast_tanh(gv[2][q] + bi_[2] + r_ * gh2);
            float hp = hl[b * 16 + cloc];
            float hn = (1.0f - z_) * n_2 + z_ * hp;
            hl[b * 16 + cloc] = hn;
            hn4[q] = hn;
            pack_store_h(hw, b, hn);
        }
        if (ydst) {
            float s0 = hn4[0] * fcwv, s1 = hn4[1] * fcwv, s2 = hn4[2] * fcwv, s3 = hn4[3] * fcwv;
            #pragma unroll
            for (int m = 1; m < 16; m <<= 1) {
                s0 += __shfl_xor(s0, m); s1 += __shfl_xor(s1, m);
                s2 += __shfl_xor(s2, m); s3 += __shfl_xor(s3, m);
            }
            if (cloc == 0) {
                atomicAdd(ydst + b0base, s0);
                atomicAdd(ydst + b0base + 1, s1);
                atomicAdd(ydst + b0base + 2, s2);
                atomicAdd(ydst + b0base + 3, s3);
            }
        }
    };

    auto load_gi = [&](const float* gr, f32x4 (&gv)[3]) {
        #pragma unroll
        for (int g = 0; g < 3; ++g) {
            union { f32x4 v; u64 u[2]; } t;
            const float* src = gr + ((size_t)g * NH + c) * NB + b0base;
            t.u[0] = ldu64(src);
            t.u[1] = ldu64(src + 2);
            gv[g] = t.v;
        }
    };

    unsigned tgt = 0, ctgt = 0;
    int cur0 = 0, cur1 = 0, gcur = 0;
    f32x4 zero4 = {0.f, 0.f, 0.f, 0.f};

    auto COPY = [&]() {   // stage current read-buffers into region, return slot base
        ++ctgt;
        int slot = (int)(ctgt & 1);
        xcopy(cur0 ? p.h0b1 : p.h0b0, cur1 ? p.h1b1 : p.h1b0, slot);
        csync(ctgt);
        return p.reg + ((size_t)(xcd_ * 2 + slot)) * 524288;
    };

    // ---- conditioning: phases 0 .. NS+1 (3-stage pipeline); y0 fused at ph==NS+1
    for (int ph = 0; ph < NS + 2; ++ph) {
        const char* regB = COPY();
        if (role == 0 && ph < NS) {
            float xv[4];
            #pragma unroll
            for (int q = 0; q < 4; ++q) xv[q] = ldf32(p.x + (size_t)(b0base + q) * NS + ph);
            f32x4 acc[3] = {zero4, zero4, zero4};
            do_gemm(regB, acc);
            l0_epi(xv, acc, cur0 ? p.h0b0 : p.h0b1);
        } else if (role == 1 && ph >= 1 && ph <= NS) {
            f32x4 acc[3] = {zero4, zero4, zero4};
            do_gemm(regB, acc);
            gi_epi(acc, gcur ? p.gib0 : p.gib1);
        } else if (role == 2 && ph >= 2) {
            f32x4 gv[3];
            load_gi(gcur ? p.gib1 : p.gib0, gv);
            f32x4 acc[3] = {zero4, zero4, zero4};
            do_gemm(regB + 262144, acc);
            gh_epi(acc, gv, cur1 ? p.h1b0 : p.h1b1, (ph == NS + 1) ? p.ys : nullptr);
        }
        ++tgt; gbar(tgt);
        if (ph < NS) cur0 ^= 1;
        if (ph >= 1 && ph <= NS) gcur ^= 1;
        if (ph >= 2) cur1 ^= 1;
    }

    // ---- forecast: 7 autoregressive steps, 3 phases each (L0 -> GI -> GH+fc)
    for (int i = 1; i < NF; ++i) {
        const char* regB = COPY();
        if (role == 0) {
            float xv[4];
            #pragma unroll
            for (int q = 0; q < 4; ++q) xv[q] = ldf32(p.ys + (i - 1) * NB + b0base + q);
            f32x4 acc[3] = {zero4, zero4, zero4};
            do_gemm(regB, acc);
            l0_epi(xv, acc, cur0 ? p.h0b0 : p.h0b1);
        }
        ++tgt; gbar(tgt); cur0 ^= 1;

        regB = COPY();
        if (role == 1) {
            f32x4 acc[3] = {zero4, zero4, zero4};
            do_gemm(regB, acc);
            gi_epi(acc, gcur ? p.gib0 : p.gib1);
        }
        ++tgt; gbar(tgt); gcur ^= 1;

        regB = COPY();
        if (role == 2) {
            f32x4 gv[3];
            load_gi(gcur ? p.gib1 : p.gib0, gv);
            f32x4 acc[3] = {zero4, zero4, zero4};
            do_gemm(regB + 262144, acc);
            gh_epi(acc, gv, cur1 ? p.h1b0 : p.h1b1, p.ys + i * NB);
        }
        ++tgt; gbar(tgt); cur1 ^= 1;
    }

    // ---- final output: mean of forecasts + h_final export from LDS
    if (bid == 0 && tid < NB) {
        float s = 0.0f;
        #pragma unroll
        for (int k = 0; k < NF; ++k) s += ldf32(p.ys + k * NB + tid);
        p.out[tid] = s * 0.125f;
    }
    if (role != 1) {
        float* ob = p.out + NB + (role == 2 ? (size_t)NB * NH : 0);
        for (int i = tid; i < NB * 16; i += NTH) {
            int b = i >> 4, cl = i & 15;
            ob[(size_t)b * NH + colbase + cl] = hl[i];
        }
    }
}

extern "C" void kernel_launch(void* const* d_in, const int* in_sizes, int n_in,
                              void* d_out, int out_size, void* d_ws, size_t ws_size,
                              hipStream_t stream)
{
    GP p;
    p.x    = (const float*)d_in[0];
    p.hin  = (const float*)d_in[1];
    p.Wih0 = (const float*)d_in[2];
    p.Whh0 = (const float*)d_in[3];
    p.bih0 = (const float*)d_in[4];
    p.bhh0 = (const float*)d_in[5];
    p.Wih1 = (const float*)d_in[6];
    p.Whh1 = (const float*)d_in[7];
    p.bih1 = (const float*)d_in[8];
    p.bhh1 = (const float*)d_in[9];
    p.fcw  = (const float*)d_in[10];
    p.fcb  = (const float*)d_in[11];
    p.out  = (float*)d_out;

    char* ws = (char*)d_ws;
    p.bar  = (unsigned*)ws;                      ws += 8192;
    p.h0b0 = (half_t*)ws;                        ws += 262144;
    p.h0b1 = (half_t*)ws;                        ws += 262144;
    p.h1b0 = (half_t*)ws;                        ws += 262144;
    p.h1b1 = (half_t*)ws;                        ws += 262144;
    p.gib0 = (float*)ws;                         ws += 1572864;
    p.gib1 = (float*)ws;                         ws += 1572864;
    p.ys   = (float*)ws;                         ws += 4096;
    ws = (char*)(((size_t)ws + 4095) & ~(size_t)4095);
    p.reg  = ws;                                 ws += 8 * 2 * 524288;   // 8 MiB

    hipMemsetAsync(p.bar, 0, 8192, stream);
    k_init<<<512, 256, 0, stream>>>(p.hin, p.h0b0, p.h1b0, p.fcb, p.ys);

    void* args[] = { &p };
    if (hipLaunchCooperativeKernel((void*)k_gru, dim3(NBLK), dim3(NTH), args,
                                   106752, stream) != hipSuccess) {
        (void)hipGetLastError();
        // fallback: 192 blocks @ ~104KiB LDS = 1 block/CU on 256 CUs -> co-resident
        k_gru<<<dim3(NBLK), dim3(NTH), 106752, stream>>>(p);
    }
}